// Round 10
// baseline (278.895 us; speedup 1.0000x reference)
//
#include <hip/hip_runtime.h>
#include <hip/hip_bf16.h>

#define N_NODES 200000
#define N_EDGES 300000
#define N_Q     128
#define N_ENT   50000
#define D       256
#define DSM     64
#define SDIM    128
#define SSM     32

typedef __attribute__((ext_vector_type(8))) short bf16x8;
typedef __attribute__((ext_vector_type(4))) float f32x4;

__device__ __forceinline__ float leaky(float x){ return x > 0.f ? x : 0.01f*x; }

__device__ __forceinline__ unsigned short f2bf(float f){
  __hip_bfloat16 h = __float2bfloat16(f);
  return *reinterpret_cast<unsigned short*>(&h);
}
__device__ __forceinline__ unsigned pk2bf(float a, float b){
  float2 t; t.x = a; t.y = b;
  __hip_bfloat162 h = __float22bfloat162_rn(t);
  return *reinterpret_cast<unsigned*>(&h);
}
__device__ __forceinline__ float bf2f(unsigned short h){
  return __uint_as_float(((unsigned)h) << 16);
}

// pack fp32 [K][N] row-major -> bf16 MFMA B-fragment order.
__device__ __forceinline__ void dev_pack(const float* __restrict__ src,
                                         unsigned short* __restrict__ dst,
                                         int K, int N, int id, int total){
  if (id >= total) return;
  int lane = id & 63, fb = id >> 6;
  int KB = K >> 5;
  int kb = fb % KB, nb = fb / KB;
  int k0 = kb*32 + ((lane>>4)<<3);
  int n  = nb*16 + (lane & 15);
  #pragma unroll
  for (int i = 0; i < 8; ++i) dst[(size_t)id*8 + i] = f2bf(src[(size_t)(k0+i)*N + n]);
}

// ---------------- fused setup stage 1 ----------------
__global__ void k_setup1(float* out, float* denom,
                         const float* __restrict__ Wp, const float* __restrict__ Wl,
                         const float* __restrict__ Wr, float* Wnlr, float* Wrlr,
                         const float* __restrict__ bp, float* cv,
                         const float* __restrict__ qsrc, const float* __restrict__ Ws,
                         const float* __restrict__ bs, const float* __restrict__ qrel,
                         float* qs, float* qr,
                         const float* __restrict__ Wbs, unsigned short* Wbs_pk,
                         const float* __restrict__ Wc, unsigned short* Wc_pk){
  int b = blockIdx.x, tid = threadIdx.x;
  if (b < 782){
    int id = b*256 + tid;
    if (id < N_ENT) out[id] = 0.f;
    if (id < N_NODES) denom[id] = 0.f;
  } else if (b < 1038){
    int id = (b-782)*256 + tid;
    int m = id >> 14, rem = id & 16383, k = rem >> 6, c = rem & 63;
    const float* Wsrc = (m & 1) ? Wr : Wl;
    int roff = (m >> 1) * 64;
    float s = 0.f;
    for (int i = 0; i < 64; ++i) s += Wp[k*64+i] * Wsrc[(roff+i)*64 + c];
    float* o = (m >> 1) ? Wrlr : Wnlr;
    o[k*128 + (m&1)*64 + c] = s;
  } else if (b == 1038){
    int m = tid >> 6, c = tid & 63;
    const float* Wsrc = (m & 1) ? Wr : Wl;
    int roff = (m >> 1) * 64;
    float s = 0.f;
    for (int i = 0; i < 64; ++i) s += bp[i] * Wsrc[(roff+i)*64 + c];
    cv[tid] = s;
  } else if (b < 1087){
    int id = (b-1039)*256 + tid;
    if (id < N_Q*SSM){
      int q = id >> 5, i = id & 31;
      float s = bs[i];
      for (int j = 0; j < SDIM; ++j) s += qsrc[q*SDIM+j] * Ws[j*SSM+i];
      qs[id] = s;
    } else {
      int id2 = id - N_Q*SSM;
      int q = id2 >> 6, i = id2 & 63;
      float s = bp[i];
      for (int j = 0; j < D; ++j) s += qrel[q*D+j] * Wp[j*DSM+i];
      qr[id2] = s;
    }
  } else if (b < 1119){
    dev_pack(Wbs, Wbs_pk, 256, 256, (b-1087)*256 + tid, 8192);
  } else {
    dev_pack(Wc, Wc_pk, 64, 64, (b-1119)*256 + tid, 512);
  }
}

// ---------------- fused setup stage 2 ----------------
__global__ void k_setup2(const float* __restrict__ qs, const float* __restrict__ qr,
                         const float* __restrict__ Wl, const float* __restrict__ bl,
                         const float* __restrict__ Wr, const float* __restrict__ br,
                         unsigned* qctx_p,
                         const float* __restrict__ Wnlr, unsigned short* Wn_pk,
                         const float* __restrict__ Wrlr, unsigned short* Wr_pk){
  int b = blockIdx.x, tid = threadIdx.x;
  if (b < 32){
    int id = b*256 + tid;                 // 8192 = 128q * 64c
    int q = id >> 6, c = id & 63;
    float sl = bl[c], sr = br[c];
    for (int i = 0; i < SSM; ++i){
      float v = qs[q*SSM+i];
      sl += v * Wl[(128+i)*64+c];
      sr += v * Wr[(128+i)*64+c];
    }
    for (int i = 0; i < DSM; ++i){
      float v = qr[q*DSM+i];
      sl += v * Wl[(160+i)*64+c];
      sr += v * Wr[(160+i)*64+c];
    }
    qctx_p[id] = pk2bf(sl, sr);
  } else if (b < 48){
    dev_pack(Wnlr, Wn_pk, 256, 128, (b-32)*256 + tid, 4096);
  } else {
    dev_pack(Wrlr, Wr_pk, 256, 128, (b-48)*256 + tid, 4096);
  }
}

// ---------------- node pipeline (MFMA) ----------------
__global__ __launch_bounds__(256) void k_node(const float* __restrict__ A,
    const unsigned short* __restrict__ Wbs_pk, const float* __restrict__ bbs,
    const unsigned short* __restrict__ Wn_pk, const float* __restrict__ cv,
    unsigned short* __restrict__ node_l, unsigned short* __restrict__ node_r){
  __shared__ char smem[32768];
  int tid = threadIdx.x;
  int row0 = blockIdx.x * 64;                      // 3125*64 == 200000
  {
    const float4* Ag = (const float4*)(A + (size_t)row0 * 256);
    #pragma unroll
    for (int it = 0; it < 16; ++it){
      int f = tid + 256*it;
      int r = f >> 6, c4 = f & 63;
      float4 v = Ag[f];
      uint2 u;
      u.x = pk2bf(v.x, v.y);
      u.y = pk2bf(v.z, v.w);
      int byte = (r << 9) + (c4 << 3);
      byte ^= (r & 7) << 4;
      *(uint2*)(smem + byte) = u;
    }
  }
  __syncthreads();
  int l = tid & 63, wn = tid >> 6;
  f32x4 acc[4][4];
  #pragma unroll
  for (int mf = 0; mf < 4; ++mf)
    #pragma unroll
    for (int nf = 0; nf < 4; ++nf) acc[mf][nf] = (f32x4){0.f,0.f,0.f,0.f};
  for (int kb = 0; kb < 8; ++kb){
    bf16x8 a[4], b[4];
    #pragma unroll
    for (int mf = 0; mf < 4; ++mf){
      int row = mf*16 + (l & 15);
      int byte = (row << 9) + kb*64 + ((l >> 4) << 4);
      byte ^= (row & 7) << 4;
      a[mf] = *(const bf16x8*)(smem + byte);
    }
    #pragma unroll
    for (int nf = 0; nf < 4; ++nf){
      int nb = wn*4 + nf;
      b[nf] = *(const bf16x8*)(Wbs_pk + ((size_t)(nb*8 + kb)*64 + l)*8);
    }
    #pragma unroll
    for (int mf = 0; mf < 4; ++mf)
      #pragma unroll
      for (int nf = 0; nf < 4; ++nf)
        acc[mf][nf] = __builtin_amdgcn_mfma_f32_16x16x32_bf16(a[mf], b[nf], acc[mf][nf], 0, 0, 0);
  }
  __syncthreads();
  #pragma unroll
  for (int mf = 0; mf < 4; ++mf)
    #pragma unroll
    for (int nf = 0; nf < 4; ++nf){
      int col = wn*64 + nf*16 + (l & 15);
      float bb = bbs[col];
      #pragma unroll
      for (int r = 0; r < 4; ++r){
        int row = mf*16 + ((l >> 4) << 2) + r;
        int byte = (row << 9) + col*2;
        byte ^= (row & 7) << 4;
        *(unsigned short*)(smem + byte) = f2bf(leaky(acc[mf][nf][r] + bb));
      }
    }
  __syncthreads();
  f32x4 acc2[4][2];
  #pragma unroll
  for (int mf = 0; mf < 4; ++mf){ acc2[mf][0] = (f32x4){0.f,0.f,0.f,0.f}; acc2[mf][1] = (f32x4){0.f,0.f,0.f,0.f}; }
  for (int kb = 0; kb < 8; ++kb){
    bf16x8 a[4], b[2];
    #pragma unroll
    for (int mf = 0; mf < 4; ++mf){
      int row = mf*16 + (l & 15);
      int byte = (row << 9) + kb*64 + ((l >> 4) << 4);
      byte ^= (row & 7) << 4;
      a[mf] = *(const bf16x8*)(smem + byte);
    }
    #pragma unroll
    for (int nf = 0; nf < 2; ++nf){
      int nb = wn*2 + nf;
      b[nf] = *(const bf16x8*)(Wn_pk + ((size_t)(nb*8 + kb)*64 + l)*8);
    }
    #pragma unroll
    for (int mf = 0; mf < 4; ++mf)
      #pragma unroll
      for (int nf = 0; nf < 2; ++nf)
        acc2[mf][nf] = __builtin_amdgcn_mfma_f32_16x16x32_bf16(a[mf], b[nf], acc2[mf][nf], 0, 0, 0);
  }
  #pragma unroll
  for (int mf = 0; mf < 4; ++mf)
    #pragma unroll
    for (int nf = 0; nf < 2; ++nf){
      int col = wn*32 + nf*16 + (l & 15);
      float cc = cv[col];
      #pragma unroll
      for (int r = 0; r < 4; ++r){
        int row = mf*16 + ((l >> 4) << 2) + r;
        unsigned short h = f2bf(acc2[mf][nf][r] + cc);
        size_t g = (size_t)(row0 + row);
        if (col < 64) node_l[g*64 + col] = h;
        else          node_r[g*64 + col - 64] = h;
      }
    }
}

// ---------------- fused rel + edge scoring (MFMA), barrier-free + front-loaded ----------------
// 64 edges/block, 4 waves; wave owns 16 edges end-to-end. All global requests
// (idx, 16 A-tile float4-pairs, 16 paired node-gathers) issue before the first
// wait. Node rows gathered PAIRED: lanes 0-31 carry edge j as uints (2 cols),
// lanes 32-63 edge j+1 -> 8+8 uint regs instead of 16+16 ushort. qctx loads
// sit in compose (L2-hot; latency hides under GEMM1 tail). Target VGPR<=128.
__global__ __launch_bounds__(256, 4) void k_edge(const float* __restrict__ relE,
    const unsigned short* __restrict__ Wr_pk, const unsigned short* __restrict__ Wc_pk,
    const float* __restrict__ cv, const float* __restrict__ bc,
    const unsigned short* __restrict__ node_l, const unsigned short* __restrict__ node_r,
    const unsigned* __restrict__ qctx_p,
    const int* __restrict__ src, const int* __restrict__ dst, const int* __restrict__ eg,
    float* __restrict__ exbuf, float* __restrict__ denom){
  __shared__ char smem[32768];
  int tid = threadIdx.x;
  int l = tid & 63, wn = tid >> 6;
  char* wbase = smem + wn*8192;
  char* sRL  = wbase;            // [16][128] bf16, swz (row&12)<<3   (4KB)
  char* sLc  = wbase + 4096;     // [16][64]  bf16, swz (row&12)<<3   (2KB)
  char* sRin = wbase + 6144;     // [16][64]  bf16, swz (row&7)<<4    (2KB)
  int e0 = blockIdx.x * 64 + wn*16;                // this wave's 16 edges

  // (1) index load: lanes 0-15 src, 16-31 dst, 32-47 eg
  int idxv;
  {
    int j = l & 15;
    int e = e0 + j;
    int ec = e < N_EDGES ? e : N_EDGES-1;
    const int* p = (l < 16) ? src : (l < 32) ? dst : eg;
    idxv = p[ec];
  }
  // (2) all 16 A-tile loads issued upfront (independent)
  int arow = e0 + (l & 15);
  if (arow >= N_EDGES) arow = N_EDGES - 1;         // clamp (invalid rows masked later)
  const float4* Rg = (const float4*)relE;
  size_t rbase = (size_t)arow * 64 + ((l >> 4) << 1);   // float4 units
  float4 av0[8], av1[8];
  #pragma unroll
  for (int kb = 0; kb < 8; ++kb){
    av0[kb] = Rg[rbase + kb*8];
    av1[kb] = Rg[rbase + kb*8 + 1];
  }
  // (3) paired node gathers: 8 loads for node_l + 8 for node_r
  unsigned nlp[8], nrp[8];
  #pragma unroll
  for (int jp = 0; jp < 8; ++jp){
    int jj = (jp << 1) + (l >> 5);              // lanes<32 -> edge 2jp, >=32 -> 2jp+1
    int s  = __shfl(idxv, jj);
    int d2 = __shfl(idxv, 16 + jj);
    int cw = (l & 31) << 1;                     // ushort col base (2 cols per lane)
    nlp[jp] = *(const unsigned*)(node_l + (size_t)s*64 + cw);
    nrp[jp] = *(const unsigned*)(node_r + (size_t)d2*64 + cw);
  }

  // (4) GEMM1: rel_lr[16][128] = A @ Wrlr ; consumes av progressively
  f32x4 acc[8];
  #pragma unroll
  for (int nb = 0; nb < 8; ++nb) acc[nb] = (f32x4){0.f,0.f,0.f,0.f};
  #pragma unroll
  for (int kb = 0; kb < 8; ++kb){
    union { bf16x8 v; unsigned u[4]; } au;
    au.u[0] = pk2bf(av0[kb].x, av0[kb].y); au.u[1] = pk2bf(av0[kb].z, av0[kb].w);
    au.u[2] = pk2bf(av1[kb].x, av1[kb].y); au.u[3] = pk2bf(av1[kb].z, av1[kb].w);
    #pragma unroll
    for (int nb = 0; nb < 8; ++nb){
      bf16x8 b = *(const bf16x8*)(Wr_pk + ((size_t)(nb*8 + kb)*64 + l)*8);
      acc[nb] = __builtin_amdgcn_mfma_f32_16x16x32_bf16(au.v, b, acc[nb], 0, 0, 0);
    }
  }
  // (5) epilogue: + cv(rel) -> sRL (wave-local)
  #pragma unroll
  for (int nb = 0; nb < 8; ++nb){
    int col = nb*16 + (l & 15);
    float cc = cv[128 + col];
    #pragma unroll
    for (int r = 0; r < 4; ++r){
      int row = ((l >> 4) << 2) + r;
      int byte = (row << 8) + (col << 1);
      byte ^= (row & 12) << 3;
      *(unsigned short*)(sRL + byte) = f2bf(acc[nb][r] + cc);
    }
  }
  // (6) compose: node rows unpacked from paired regs; qctx from L1/L2
  #pragma unroll
  for (int j = 0; j < 16; ++j){
    int e = e0 + j;
    int byteL = (j << 8) + (l << 1);        byteL ^= (j & 12) << 3;
    int byteR = (j << 8) + ((64+l) << 1);   byteR ^= (j & 12) << 3;
    int bL = (j << 7) + (l << 1);           bL ^= (j & 12) << 3;
    int bR = (j << 7) + (l << 1);           bR ^= (j & 7) << 4;
    unsigned short lh16 = 0, rr16 = 0;
    if (e < N_EDGES){
      int b = __shfl(idxv, 32 + j);
      unsigned qv = qctx_p[b*64 + l];
      unsigned ul = __shfl(nlp[j >> 1], ((j & 1) << 5) + (l >> 1));
      unsigned ur = __shfl(nrp[j >> 1], ((j & 1) << 5) + (l >> 1));
      unsigned short nl16 = (l & 1) ? (unsigned short)(ul >> 16) : (unsigned short)(ul & 0xFFFFu);
      unsigned short nr16 = (l & 1) ? (unsigned short)(ur >> 16) : (unsigned short)(ur & 0xFFFFu);
      float lh = leaky(bf2f(nl16) + bf2f(*(unsigned short*)(sRL + byteL))
                       + bf2f((unsigned short)(qv & 0xFFFFu)));
      float rr = leaky(bf2f(nr16) + bf2f(*(unsigned short*)(sRL + byteR))
                       + bf2f((unsigned short)(qv >> 16)));
      lh16 = f2bf(lh); rr16 = f2bf(rr);
    }
    *(unsigned short*)(sLc + bL) = lh16;
    *(unsigned short*)(sRin + bR) = rr16;
  }
  // (7) GEMM2: RH[16][64] = sRin @ Wc (wave-local)
  float bcv[4];
  #pragma unroll
  for (int nf = 0; nf < 4; ++nf) bcv[nf] = bc[nf*16 + (l & 15)];
  f32x4 acc2[4];
  #pragma unroll
  for (int nf = 0; nf < 4; ++nf) acc2[nf] = (f32x4){0.f,0.f,0.f,0.f};
  #pragma unroll
  for (int kb = 0; kb < 2; ++kb){
    int row = l & 15;
    int byte = (row << 7) + kb*64 + ((l >> 4) << 4);
    byte ^= (row & 7) << 4;
    bf16x8 a = *(const bf16x8*)(sRin + byte);
    #pragma unroll
    for (int nf = 0; nf < 4; ++nf){
      bf16x8 bfr = *(const bf16x8*)(Wc_pk + ((size_t)(nf*2 + kb)*64 + l)*8);
      acc2[nf] = __builtin_amdgcn_mfma_f32_16x16x32_bf16(a, bfr, acc2[nf], 0, 0, 0);
    }
  }
  // (8) logit = sum_col (RH+bc)*lh, 16-lane-group reduce; tail: exp + denom atomic
  int srcj[4];
  float vr[4];
  #pragma unroll
  for (int r = 0; r < 4; ++r){
    int rowl = ((l >> 4) << 2) + r;
    srcj[r] = __shfl(idxv, rowl);
    float v = 0.f;
    #pragma unroll
    for (int nf = 0; nf < 4; ++nf){
      int col = nf*16 + (l & 15);
      int byte = (rowl << 7) + (col << 1);
      byte ^= (rowl & 12) << 3;
      v += (acc2[nf][r] + bcv[nf]) * bf2f(*(unsigned short*)(sLc + byte));
    }
    v += __shfl_xor(v, 1); v += __shfl_xor(v, 2);
    v += __shfl_xor(v, 4); v += __shfl_xor(v, 8);
    vr[r] = v;
  }
  if ((l & 15) == 0){
    #pragma unroll
    for (int r = 0; r < 4; ++r){
      int rowl = ((l >> 4) << 2) + r;
      int e = e0 + rowl;
      if (e < N_EDGES){
        float ex = __expf(vr[r]);
        exbuf[e] = ex;
        atomicAdd(&denom[srcj[r]], ex);
      }
    }
  }
}

// ---------------- final pass: trans + propagate + entity aggregate ----------------
__global__ void k_passC(const float* __restrict__ exbuf, const float* __restrict__ denom,
                        const int* __restrict__ src, const int* __restrict__ dst,
                        const float* __restrict__ node_score, const int* __restrict__ ent,
                        float* __restrict__ out){
  int e = blockIdx.x*256 + threadIdx.x;
  if (e >= N_EDGES) return;
  int s = src[e];
  float tr = exbuf[e] / denom[s];
  atomicAdd(&out[ent[dst[e]]], tr * node_score[s]);
}

// ---------------- host ----------------
extern "C" void kernel_launch(void* const* d_in, const int* in_sizes, int n_in,
                              void* d_out, int out_size, void* d_ws, size_t ws_size,
                              hipStream_t stream){
  const float* mem   = (const float*)d_in[0];
  const float* nsc   = (const float*)d_in[1];
  const float* relE  = (const float*)d_in[2];
  const float* qsrc  = (const float*)d_in[3];
  const float* qrel  = (const float*)d_in[4];
  const int*   eg    = (const int*)d_in[5];
  const int*   src   = (const int*)d_in[6];
  const int*   dst   = (const int*)d_in[7];
  const int*   ent   = (const int*)d_in[8];
  const float* Wp    = (const float*)d_in[9];
  const float* bp    = (const float*)d_in[10];
  const float* Ws    = (const float*)d_in[11];
  const float* bs    = (const float*)d_in[12];
  const float* Wbs   = (const float*)d_in[13];
  const float* bbs   = (const float*)d_in[14];
  const float* Wl    = (const float*)d_in[15];
  const float* bl    = (const float*)d_in[16];
  const float* Wr    = (const float*)d_in[17];
  const float* br    = (const float*)d_in[18];
  const float* Wc    = (const float*)d_in[19];
  const float* bc    = (const float*)d_in[20];
  float* out = (float*)d_out;

  char* w = (char*)d_ws;
  auto alloc = [&](size_t bytes)->void*{
    void* p = (void*)w; w += (bytes + 255) & ~(size_t)255; return p;
  };
  float* Wnlr = (float*)alloc(32768*4);
  float* Wrlr = (float*)alloc(32768*4);
  unsigned short* Wbs_pk = (unsigned short*)alloc(65536*2);
  unsigned short* Wn_pk  = (unsigned short*)alloc(32768*2);
  unsigned short* Wr_pk  = (unsigned short*)alloc(32768*2);
  unsigned short* Wc_pk  = (unsigned short*)alloc(4096*2);
  float* cv  = (float*)alloc(256*4);
  float* qs  = (float*)alloc((size_t)N_Q*SSM*4);
  float* qr  = (float*)alloc((size_t)N_Q*DSM*4);
  unsigned* qctx_p = (unsigned*)alloc((size_t)N_Q*DSM*4);
  unsigned short* node_l = (unsigned short*)alloc((size_t)N_NODES*64*2);
  unsigned short* node_r = (unsigned short*)alloc((size_t)N_NODES*64*2);
  float* exbuf  = (float*)alloc((size_t)N_EDGES*4);
  float* denom = (float*)alloc((size_t)N_NODES*4);

  k_setup1<<<1121, 256, 0, stream>>>(out, denom,
                                     Wp, Wl, Wr, Wnlr, Wrlr, bp, cv,
                                     qsrc, Ws, bs, qrel, qs, qr,
                                     Wbs, Wbs_pk, Wc, Wc_pk);
  k_setup2<<<64, 256, 0, stream>>>(qs, qr, Wl, bl, Wr, br, qctx_p,
                                   Wnlr, Wn_pk, Wrlr, Wr_pk);
  k_node<<<N_NODES/64, 256, 0, stream>>>(mem, Wbs_pk, bbs, Wn_pk, cv, node_l, node_r);
  k_edge<<<(N_EDGES+63)/64, 256, 0, stream>>>(relE, Wr_pk, Wc_pk, cv, bc,
                                              node_l, node_r, qctx_p,
                                              src, dst, eg, exbuf, denom);
  k_passC<<<(N_EDGES+255)/256, 256, 0, stream>>>(exbuf, denom, src, dst, nsc, ent, out);
}

// Round 11
// 231.068 us; speedup vs baseline: 1.2070x; 1.2070x over previous
//
#include <hip/hip_runtime.h>
#include <hip/hip_bf16.h>

#define N_NODES 200000
#define N_EDGES 300000
#define N_Q     128
#define N_ENT   50000
#define D       256
#define DSM     64
#define SDIM    128
#define SSM     32

#define NODE_BLKS 3125
#define REL_BLKS  4688

typedef __attribute__((ext_vector_type(8))) short bf16x8;
typedef __attribute__((ext_vector_type(4))) float f32x4;

__device__ __forceinline__ float leaky(float x){ return x > 0.f ? x : 0.01f*x; }

__device__ __forceinline__ unsigned short f2bf(float f){
  __hip_bfloat16 h = __float2bfloat16(f);
  return *reinterpret_cast<unsigned short*>(&h);
}
__device__ __forceinline__ unsigned pk2bf(float a, float b){
  float2 t; t.x = a; t.y = b;
  __hip_bfloat162 h = __float22bfloat162_rn(t);
  return *reinterpret_cast<unsigned*>(&h);
}
__device__ __forceinline__ float bf2f(unsigned short h){
  return __uint_as_float(((unsigned)h) << 16);
}

// pack fp32 [K][N] row-major -> bf16 MFMA B-fragment order.
__device__ __forceinline__ void dev_pack(const float* __restrict__ src,
                                         unsigned short* __restrict__ dst,
                                         int K, int N, int id, int total){
  if (id >= total) return;
  int lane = id & 63, fb = id >> 6;
  int KB = K >> 5;
  int kb = fb % KB, nb = fb / KB;
  int k0 = kb*32 + ((lane>>4)<<3);
  int n  = nb*16 + (lane & 15);
  #pragma unroll
  for (int i = 0; i < 8; ++i) dst[(size_t)id*8 + i] = f2bf(src[(size_t)(k0+i)*N + n]);
}

// ---------------- fused setup stage 1 ----------------
__global__ void k_setup1(float* out, float* denom,
                         const float* __restrict__ Wp, const float* __restrict__ Wl,
                         const float* __restrict__ Wr, float* Wnlr, float* Wrlr,
                         const float* __restrict__ bp, float* cv,
                         const float* __restrict__ qsrc, const float* __restrict__ Ws,
                         const float* __restrict__ bs, const float* __restrict__ qrel,
                         float* qs, float* qr,
                         const float* __restrict__ Wbs, unsigned short* Wbs_pk,
                         const float* __restrict__ Wc, unsigned short* Wc_pk){
  int b = blockIdx.x, tid = threadIdx.x;
  if (b < 782){
    int id = b*256 + tid;
    if (id < N_ENT) out[id] = 0.f;
    if (id < N_NODES) denom[id] = 0.f;
  } else if (b < 1038){
    int id = (b-782)*256 + tid;
    int m = id >> 14, rem = id & 16383, k = rem >> 6, c = rem & 63;
    const float* Wsrc = (m & 1) ? Wr : Wl;
    int roff = (m >> 1) * 64;
    float s = 0.f;
    for (int i = 0; i < 64; ++i) s += Wp[k*64+i] * Wsrc[(roff+i)*64 + c];
    float* o = (m >> 1) ? Wrlr : Wnlr;
    o[k*128 + (m&1)*64 + c] = s;
  } else if (b == 1038){
    int m = tid >> 6, c = tid & 63;
    const float* Wsrc = (m & 1) ? Wr : Wl;
    int roff = (m >> 1) * 64;
    float s = 0.f;
    for (int i = 0; i < 64; ++i) s += bp[i] * Wsrc[(roff+i)*64 + c];
    cv[tid] = s;
  } else if (b < 1087){
    int id = (b-1039)*256 + tid;
    if (id < N_Q*SSM){
      int q = id >> 5, i = id & 31;
      float s = bs[i];
      for (int j = 0; j < SDIM; ++j) s += qsrc[q*SDIM+j] * Ws[j*SSM+i];
      qs[id] = s;
    } else {
      int id2 = id - N_Q*SSM;
      int q = id2 >> 6, i = id2 & 63;
      float s = bp[i];
      for (int j = 0; j < D; ++j) s += qrel[q*D+j] * Wp[j*DSM+i];
      qr[id2] = s;
    }
  } else if (b < 1119){
    dev_pack(Wbs, Wbs_pk, 256, 256, (b-1087)*256 + tid, 8192);
  } else {
    dev_pack(Wc, Wc_pk, 64, 64, (b-1119)*256 + tid, 512);
  }
}

// ---------------- fused setup stage 2 ----------------
__global__ void k_setup2(const float* __restrict__ qs, const float* __restrict__ qr,
                         const float* __restrict__ Wl, const float* __restrict__ bl,
                         const float* __restrict__ Wr, const float* __restrict__ br,
                         unsigned* qctx_p,
                         const float* __restrict__ Wnlr, unsigned short* Wn_pk,
                         const float* __restrict__ Wrlr, unsigned short* Wr_pk){
  int b = blockIdx.x, tid = threadIdx.x;
  if (b < 32){
    int id = b*256 + tid;                 // 8192 = 128q * 64c
    int q = id >> 6, c = id & 63;
    float sl = bl[c], sr = br[c];
    for (int i = 0; i < SSM; ++i){
      float v = qs[q*SSM+i];
      sl += v * Wl[(128+i)*64+c];
      sr += v * Wr[(128+i)*64+c];
    }
    for (int i = 0; i < DSM; ++i){
      float v = qr[q*DSM+i];
      sl += v * Wl[(160+i)*64+c];
      sr += v * Wr[(160+i)*64+c];
    }
    qctx_p[id] = pk2bf(sl, sr);
  } else if (b < 48){
    dev_pack(Wnlr, Wn_pk, 256, 128, (b-32)*256 + tid, 4096);
  } else {
    dev_pack(Wrlr, Wr_pk, 256, 128, (b-48)*256 + tid, 4096);
  }
}

// ---------------- fused projection kernel: node GEMM + rel GEMM interleaved ----------------
// Groups of 5 blocks: 2 node-blocks + 3 rel-blocks (ratio 3125:4688), so both
// phases are co-resident machine-wide: node's MFMA/barrier stalls absorb rel's
// HBM waits and vice versa (m114: co-scheduled time ~= max, not sum).
__global__ __launch_bounds__(256) void k_proj(const float* __restrict__ A,
    const unsigned short* __restrict__ Wbs_pk, const float* __restrict__ bbs,
    const unsigned short* __restrict__ Wn_pk, const float* __restrict__ cv,
    unsigned short* __restrict__ node_l, unsigned short* __restrict__ node_r,
    const float* __restrict__ relE, const unsigned short* __restrict__ Wr_pk,
    unsigned* __restrict__ rel_pk){
  __shared__ char smem[32768];
  int tid = threadIdx.x;
  int l = tid & 63, wn = tid >> 6;
  int g = blockIdx.x / 5, r5 = blockIdx.x % 5;

  if (r5 < 2){
    // ---------- node path ----------
    int nb = g*2 + r5;
    if (nb >= NODE_BLKS) return;
    int row0 = nb * 64;
    {
      const float4* Ag = (const float4*)(A + (size_t)row0 * 256);
      #pragma unroll
      for (int it = 0; it < 16; ++it){
        int f = tid + 256*it;
        int r = f >> 6, c4 = f & 63;
        float4 v = Ag[f];
        uint2 u;
        u.x = pk2bf(v.x, v.y);
        u.y = pk2bf(v.z, v.w);
        int byte = (r << 9) + (c4 << 3);
        byte ^= (r & 7) << 4;
        *(uint2*)(smem + byte) = u;
      }
    }
    __syncthreads();
    f32x4 acc[4][4];
    #pragma unroll
    for (int mf = 0; mf < 4; ++mf)
      #pragma unroll
      for (int nf = 0; nf < 4; ++nf) acc[mf][nf] = (f32x4){0.f,0.f,0.f,0.f};
    for (int kb = 0; kb < 8; ++kb){
      bf16x8 a[4], b[4];
      #pragma unroll
      for (int mf = 0; mf < 4; ++mf){
        int row = mf*16 + (l & 15);
        int byte = (row << 9) + kb*64 + ((l >> 4) << 4);
        byte ^= (row & 7) << 4;
        a[mf] = *(const bf16x8*)(smem + byte);
      }
      #pragma unroll
      for (int nf = 0; nf < 4; ++nf){
        int nbb = wn*4 + nf;
        b[nf] = *(const bf16x8*)(Wbs_pk + ((size_t)(nbb*8 + kb)*64 + l)*8);
      }
      #pragma unroll
      for (int mf = 0; mf < 4; ++mf)
        #pragma unroll
        for (int nf = 0; nf < 4; ++nf)
          acc[mf][nf] = __builtin_amdgcn_mfma_f32_16x16x32_bf16(a[mf], b[nf], acc[mf][nf], 0, 0, 0);
    }
    __syncthreads();
    #pragma unroll
    for (int mf = 0; mf < 4; ++mf)
      #pragma unroll
      for (int nf = 0; nf < 4; ++nf){
        int col = wn*64 + nf*16 + (l & 15);
        float bb = bbs[col];
        #pragma unroll
        for (int r = 0; r < 4; ++r){
          int row = mf*16 + ((l >> 4) << 2) + r;
          int byte = (row << 9) + col*2;
          byte ^= (row & 7) << 4;
          *(unsigned short*)(smem + byte) = f2bf(leaky(acc[mf][nf][r] + bb));
        }
      }
    __syncthreads();
    f32x4 acc2[4][2];
    #pragma unroll
    for (int mf = 0; mf < 4; ++mf){ acc2[mf][0] = (f32x4){0.f,0.f,0.f,0.f}; acc2[mf][1] = (f32x4){0.f,0.f,0.f,0.f}; }
    for (int kb = 0; kb < 8; ++kb){
      bf16x8 a[4], b[2];
      #pragma unroll
      for (int mf = 0; mf < 4; ++mf){
        int row = mf*16 + (l & 15);
        int byte = (row << 9) + kb*64 + ((l >> 4) << 4);
        byte ^= (row & 7) << 4;
        a[mf] = *(const bf16x8*)(smem + byte);
      }
      #pragma unroll
      for (int nf = 0; nf < 2; ++nf){
        int nbb = wn*2 + nf;
        b[nf] = *(const bf16x8*)(Wn_pk + ((size_t)(nbb*8 + kb)*64 + l)*8);
      }
      #pragma unroll
      for (int mf = 0; mf < 4; ++mf)
        #pragma unroll
        for (int nf = 0; nf < 2; ++nf)
          acc2[mf][nf] = __builtin_amdgcn_mfma_f32_16x16x32_bf16(a[mf], b[nf], acc2[mf][nf], 0, 0, 0);
    }
    #pragma unroll
    for (int mf = 0; mf < 4; ++mf)
      #pragma unroll
      for (int nf = 0; nf < 2; ++nf){
        int col = wn*32 + nf*16 + (l & 15);
        float cc = cv[col];
        #pragma unroll
        for (int r = 0; r < 4; ++r){
          int row = mf*16 + ((l >> 4) << 2) + r;
          unsigned short h = f2bf(acc2[mf][nf][r] + cc);
          size_t gg = (size_t)(row0 + row);
          if (col < 64) node_l[gg*64 + col] = h;
          else          node_r[gg*64 + col - 64] = h;
        }
      }
  } else {
    // ---------- rel path ----------
    int rb = g*3 + (r5 - 2);
    if (rb >= REL_BLKS) return;
    int row0 = rb * 64;
    {
      const float4* Rg = (const float4*)relE;
      #pragma unroll
      for (int it = 0; it < 16; ++it){
        int f = tid + 256*it;
        int r = f >> 6, c4 = f & 63;
        int ge = row0 + r; if (ge >= N_EDGES) ge = N_EDGES-1;
        float4 v = Rg[(size_t)ge*64 + c4];
        uint2 u;
        u.x = pk2bf(v.x, v.y);
        u.y = pk2bf(v.z, v.w);
        int byte = (r << 9) + (c4 << 3);
        byte ^= (r & 7) << 4;
        *(uint2*)(smem + byte) = u;
      }
    }
    __syncthreads();
    f32x4 acc[4][2];
    #pragma unroll
    for (int mf = 0; mf < 4; ++mf){ acc[mf][0] = (f32x4){0.f,0.f,0.f,0.f}; acc[mf][1] = (f32x4){0.f,0.f,0.f,0.f}; }
    for (int kb = 0; kb < 8; ++kb){
      bf16x8 a[4], b0, b1;
      #pragma unroll
      for (int mf = 0; mf < 4; ++mf){
        int row = mf*16 + (l & 15);
        int byte = (row << 9) + kb*64 + ((l >> 4) << 4);
        byte ^= (row & 7) << 4;
        a[mf] = *(const bf16x8*)(smem + byte);
      }
      b0 = *(const bf16x8*)(Wr_pk + ((size_t)(wn*8 + kb)*64 + l)*8);        // left  nb=wn
      b1 = *(const bf16x8*)(Wr_pk + ((size_t)((4+wn)*8 + kb)*64 + l)*8);    // right nb=4+wn
      #pragma unroll
      for (int mf = 0; mf < 4; ++mf){
        acc[mf][0] = __builtin_amdgcn_mfma_f32_16x16x32_bf16(a[mf], b0, acc[mf][0], 0, 0, 0);
        acc[mf][1] = __builtin_amdgcn_mfma_f32_16x16x32_bf16(a[mf], b1, acc[mf][1], 0, 0, 0);
      }
    }
    int c = wn*16 + (l & 15);
    float cvL = cv[128 + c], cvR = cv[192 + c];
    #pragma unroll
    for (int mf = 0; mf < 4; ++mf)
      #pragma unroll
      for (int r = 0; r < 4; ++r){
        int row = mf*16 + ((l >> 4) << 2) + r;
        int e = row0 + row;
        if (e < N_EDGES)
          rel_pk[(size_t)e*64 + c] = pk2bf(acc[mf][0][r] + cvL, acc[mf][1][r] + cvR);
      }
  }
}

// ---------------- edge scoring (compose + GEMM2 + logit), barrier-free ----------------
// 64 edges/block, 4 waves; wave owns 16 edges. Front-loads 16 packed-rel uints
// + 32 node gathers (one stall/wave); 4KB wave-private LDS; high occupancy.
__global__ __launch_bounds__(256, 4) void k_score(const unsigned* __restrict__ rel_pk,
    const unsigned short* __restrict__ Wc_pk, const float* __restrict__ bc,
    const unsigned short* __restrict__ node_l, const unsigned short* __restrict__ node_r,
    const unsigned* __restrict__ qctx_p,
    const int* __restrict__ src, const int* __restrict__ dst, const int* __restrict__ eg,
    float* __restrict__ exbuf, float* __restrict__ denom){
  __shared__ char smem[16384];
  int tid = threadIdx.x;
  int l = tid & 63, wn = tid >> 6;
  char* wbase = smem + wn*4096;
  char* sLc  = wbase;            // [16][64] bf16, swz (row&12)<<3  (2KB)
  char* sRin = wbase + 2048;     // [16][64] bf16, swz (row&7)<<4   (2KB)
  int e0 = blockIdx.x * 64 + wn*16;

  // (1) index load: lanes 0-15 src, 16-31 dst, 32-47 eg
  int idxv;
  {
    int j = l & 15;
    int e = e0 + j;
    int ec = e < N_EDGES ? e : N_EDGES-1;
    const int* p = (l < 16) ? src : (l < 32) ? dst : eg;
    idxv = p[ec];
  }
  // (2) front-load: rel rows (coalesced, L3-hot) + node gathers
  unsigned rlrv[16];
  unsigned short nlv[16], nrv[16];
  #pragma unroll
  for (int j = 0; j < 16; ++j){
    int e = e0 + j;
    int ec = e < N_EDGES ? e : N_EDGES-1;
    rlrv[j] = rel_pk[(size_t)ec*64 + l];
    int s  = __shfl(idxv, j);
    int d2 = __shfl(idxv, 16 + j);
    nlv[j] = node_l[(size_t)s*64 + l];
    nrv[j] = node_r[(size_t)d2*64 + l];
  }
  // (3) compose -> sLc/sRin (wave-local)
  #pragma unroll
  for (int j = 0; j < 16; ++j){
    int e = e0 + j;
    int bL = (j << 7) + (l << 1);  bL ^= (j & 12) << 3;
    int bR = (j << 7) + (l << 1);  bR ^= (j & 7) << 4;
    unsigned short lh16 = 0, rr16 = 0;
    if (e < N_EDGES){
      int b = __shfl(idxv, 32 + j);
      unsigned qv = qctx_p[b*64 + l];
      unsigned rv = rlrv[j];
      float lh = leaky(bf2f(nlv[j]) + bf2f((unsigned short)(rv & 0xFFFFu))
                       + bf2f((unsigned short)(qv & 0xFFFFu)));
      float rr = leaky(bf2f(nrv[j]) + bf2f((unsigned short)(rv >> 16))
                       + bf2f((unsigned short)(qv >> 16)));
      lh16 = f2bf(lh); rr16 = f2bf(rr);
    }
    *(unsigned short*)(sLc + bL) = lh16;
    *(unsigned short*)(sRin + bR) = rr16;
  }
  // (4) GEMM2: RH[16][64] = sRin @ Wc (wave-local)
  float bcv[4];
  #pragma unroll
  for (int nf = 0; nf < 4; ++nf) bcv[nf] = bc[nf*16 + (l & 15)];
  f32x4 acc2[4];
  #pragma unroll
  for (int nf = 0; nf < 4; ++nf) acc2[nf] = (f32x4){0.f,0.f,0.f,0.f};
  #pragma unroll
  for (int kb = 0; kb < 2; ++kb){
    int row = l & 15;
    int byte = (row << 7) + kb*64 + ((l >> 4) << 4);
    byte ^= (row & 7) << 4;
    bf16x8 a = *(const bf16x8*)(sRin + byte);
    #pragma unroll
    for (int nf = 0; nf < 4; ++nf){
      bf16x8 bfr = *(const bf16x8*)(Wc_pk + ((size_t)(nf*2 + kb)*64 + l)*8);
      acc2[nf] = __builtin_amdgcn_mfma_f32_16x16x32_bf16(a, bfr, acc2[nf], 0, 0, 0);
    }
  }
  // (5) logit = sum_col (RH+bc)*lh, 16-lane-group reduce; tail: exp + denom atomic
  int srcj[4];
  float vr[4];
  #pragma unroll
  for (int r = 0; r < 4; ++r){
    int rowl = ((l >> 4) << 2) + r;
    srcj[r] = __shfl(idxv, rowl);
    float v = 0.f;
    #pragma unroll
    for (int nf = 0; nf < 4; ++nf){
      int col = nf*16 + (l & 15);
      int byte = (rowl << 7) + (col << 1);
      byte ^= (rowl & 12) << 3;
      v += (acc2[nf][r] + bcv[nf]) * bf2f(*(unsigned short*)(sLc + byte));
    }
    v += __shfl_xor(v, 1); v += __shfl_xor(v, 2);
    v += __shfl_xor(v, 4); v += __shfl_xor(v, 8);
    vr[r] = v;
  }
  if ((l & 15) == 0){
    #pragma unroll
    for (int r = 0; r < 4; ++r){
      int rowl = ((l >> 4) << 2) + r;
      int e = e0 + rowl;
      if (e < N_EDGES){
        float ex = __expf(vr[r]);
        exbuf[e] = ex;
        atomicAdd(&denom[srcj[r]], ex);
      }
    }
  }
}

// ---------------- final pass: trans + propagate + entity aggregate ----------------
__global__ void k_passC(const float* __restrict__ exbuf, const float* __restrict__ denom,
                        const int* __restrict__ src, const int* __restrict__ dst,
                        const float* __restrict__ node_score, const int* __restrict__ ent,
                        float* __restrict__ out){
  int e = blockIdx.x*256 + threadIdx.x;
  if (e >= N_EDGES) return;
  int s = src[e];
  float tr = exbuf[e] / denom[s];
  atomicAdd(&out[ent[dst[e]]], tr * node_score[s]);
}

// ---------------- host ----------------
extern "C" void kernel_launch(void* const* d_in, const int* in_sizes, int n_in,
                              void* d_out, int out_size, void* d_ws, size_t ws_size,
                              hipStream_t stream){
  const float* mem   = (const float*)d_in[0];
  const float* nsc   = (const float*)d_in[1];
  const float* relE  = (const float*)d_in[2];
  const float* qsrc  = (const float*)d_in[3];
  const float* qrel  = (const float*)d_in[4];
  const int*   eg    = (const int*)d_in[5];
  const int*   src   = (const int*)d_in[6];
  const int*   dst   = (const int*)d_in[7];
  const int*   ent   = (const int*)d_in[8];
  const float* Wp    = (const float*)d_in[9];
  const float* bp    = (const float*)d_in[10];
  const float* Ws    = (const float*)d_in[11];
  const float* bs    = (const float*)d_in[12];
  const float* Wbs   = (const float*)d_in[13];
  const float* bbs   = (const float*)d_in[14];
  const float* Wl    = (const float*)d_in[15];
  const float* bl    = (const float*)d_in[16];
  const float* Wr    = (const float*)d_in[17];
  const float* br    = (const float*)d_in[18];
  const float* Wc    = (const float*)d_in[19];
  const float* bc    = (const float*)d_in[20];
  float* out = (float*)d_out;

  char* w = (char*)d_ws;
  auto alloc = [&](size_t bytes)->void*{
    void* p = (void*)w; w += (bytes + 255) & ~(size_t)255; return p;
  };
  float* Wnlr = (float*)alloc(32768*4);
  float* Wrlr = (float*)alloc(32768*4);
  unsigned short* Wbs_pk = (unsigned short*)alloc(65536*2);
  unsigned short* Wn_pk  = (unsigned short*)alloc(32768*2);
  unsigned short* Wr_pk  = (unsigned short*)alloc(32768*2);
  unsigned short* Wc_pk  = (unsigned short*)alloc(4096*2);
  float* cv  = (float*)alloc(256*4);
  float* qs  = (float*)alloc((size_t)N_Q*SSM*4);
  float* qr  = (float*)alloc((size_t)N_Q*DSM*4);
  unsigned* qctx_p = (unsigned*)alloc((size_t)N_Q*DSM*4);
  unsigned short* node_l = (unsigned short*)alloc((size_t)N_NODES*64*2);
  unsigned short* node_r = (unsigned short*)alloc((size_t)N_NODES*64*2);
  unsigned* rel_pk = (unsigned*)alloc((size_t)N_EDGES*64*4);
  float* exbuf  = (float*)alloc((size_t)N_EDGES*4);
  float* denom = (float*)alloc((size_t)N_NODES*4);

  k_setup1<<<1121, 256, 0, stream>>>(out, denom,
                                     Wp, Wl, Wr, Wnlr, Wrlr, bp, cv,
                                     qsrc, Ws, bs, qrel, qs, qr,
                                     Wbs, Wbs_pk, Wc, Wc_pk);
  k_setup2<<<64, 256, 0, stream>>>(qs, qr, Wl, bl, Wr, br, qctx_p,
                                   Wnlr, Wn_pk, Wrlr, Wr_pk);
  k_proj<<<1563*5, 256, 0, stream>>>(mem, Wbs_pk, bbs, Wn_pk, cv, node_l, node_r,
                                     relE, Wr_pk, rel_pk);
  k_score<<<(N_EDGES+63)/64, 256, 0, stream>>>(rel_pk, Wc_pk, bc, node_l, node_r, qctx_p,
                                               src, dst, eg, exbuf, denom);
  k_passC<<<(N_EDGES+255)/256, 256, 0, stream>>>(exbuf, denom, src, dst, nsc, ent, out);
}